// Round 1
// baseline (227.867 us; speedup 1.0000x reference)
//
#include <hip/hip_runtime.h>

#define NB 512
#define NV 64
#define ND 32
#define NH 64
#define NE 4032

typedef short s16x8 __attribute__((ext_vector_type(8)));
typedef float f32x4 __attribute__((ext_vector_type(4)));

#define HLOG2PI 0.9189385332046727f
#define LOG2C   0.6931471805599453f

__device__ __forceinline__ unsigned short f2bf(float f){
  unsigned int u = __float_as_uint(f);
  u += 0x7FFFu + ((u >> 16) & 1u);
  return (unsigned short)(u >> 16);
}

// load 8 contiguous f32, convert to bf16, store as one 16B LDS chunk
__device__ __forceinline__ void stage8(const float* __restrict__ src, unsigned short* dst){
  const float4* s4 = (const float4*)src;
  float4 a = s4[0], b = s4[1];
  s16x8 v;
  v[0]=(short)f2bf(a.x); v[1]=(short)f2bf(a.y); v[2]=(short)f2bf(a.z); v[3]=(short)f2bf(a.w);
  v[4]=(short)f2bf(b.x); v[5]=(short)f2bf(b.y); v[6]=(short)f2bf(b.z); v[7]=(short)f2bf(b.w);
  *(s16x8*)dst = v;
}

// ---------------- setup kernels (run every launch; ws is re-poisoned) --------

__global__ __launch_bounds__(256) void k_bucket(const int* __restrict__ recv,
                                               int* __restrict__ bucket,
                                               int* __restrict__ counts){
  __shared__ int cnt[NV];
  int t = threadIdx.x;
  if (t < NV) cnt[t] = 0;
  __syncthreads();
  for (int e = t; e < NE; e += 256){
    int v = recv[e];
    int p = atomicAdd(&cnt[v], 1);
    bucket[v*64 + p] = e;
  }
  __syncthreads();
  if (t < NV) counts[t] = cnt[t];
}

// bf16-convert + transpose + XOR-swizzle all weight matrices into ws.
// layout (ushort idx): col j row of RL ushorts; element k at
//   j*RL + ((k>>3)^(j&7))*8 + (k&7)
__global__ __launch_bounds__(256) void k_prep(
    const float* __restrict__ m1w, const float* __restrict__ m2w,
    const float* __restrict__ f1w, const float* __restrict__ f2w,
    const float* __restrict__ muw, const float* __restrict__ lsw,
    unsigned short* __restrict__ W1s, unsigned short* __restrict__ W2s,
    unsigned short* __restrict__ F1s, unsigned short* __restrict__ F2s,
    unsigned short* __restrict__ HWs)
{
  int m = blockIdx.y;
  int idx = blockIdx.x*256 + threadIdx.x;
  if (m == 0){
    if (idx < 4096){ int k = idx>>6, j = idx&63;
      W1s[j*64 + (((k>>3)^(j&7))<<3) + (k&7)] = f2bf(m1w[idx]); }
  } else if (m == 1){
    if (idx < 4096){ int k = idx>>6, j = idx&63;
      W2s[j*64 + (((k>>3)^(j&7))<<3) + (k&7)] = f2bf(m2w[idx]); }
  } else if (m == 2){
    if (idx < 6144){ int k = idx>>6, j = idx&63;   // fc1_w is [96][64]
      F1s[j*128 + (((k>>3)^(j&7))<<3) + (k&7)] = f2bf(f1w[idx]); }
  } else if (m == 3){
    if (idx < 4096){ int k = idx>>6, j = idx&63;
      F2s[j*64 + (((k>>3)^(j&7))<<3) + (k&7)] = f2bf(f2w[idx]); }
  } else {
    if (idx < 1024){ int k = idx>>4, j = idx&15;   // head: cols 0..7 mu, 8..15 ls
      float s = (j < 8) ? muw[k*8 + j] : lsw[k*8 + (j-8)];
      HWs[j*64 + (((k>>3)^(j&7))<<3) + (k&7)] = f2bf(s); }
  }
}

// ---------------- kernel 1: edge MLP grouped by receiver ---------------------
// one block per (b,v): 64 rows (63 real edges + dummy w=0), two 64x64 bf16 MFMA
// GEMMs, weighted row-sum -> writes aug[b,v,:] (x copy + agg), no atomics.

__global__ __launch_bounds__(256) void k_msg(
    const float* __restrict__ x, const float* __restrict__ edges,
    const int* __restrict__ send, const int* __restrict__ bucket,
    const int* __restrict__ counts,
    const unsigned short* __restrict__ W1g, const unsigned short* __restrict__ W2g,
    const float* __restrict__ b1g, const float* __restrict__ b2g,
    float* __restrict__ out_aug)
{
  __shared__ __align__(16) unsigned char smem[34304];
  unsigned short* A1 = (unsigned short*)(smem);          // [64][64] bf16 swz
  unsigned short* Hs = (unsigned short*)(smem + 8192);   // [64][64] bf16 swz
  unsigned short* W1 = (unsigned short*)(smem + 16384);
  unsigned short* W2 = (unsigned short*)(smem + 24576);
  float* wrow = (float*)(smem + 32768);
  int*   srow = (int*)  (smem + 33024);
  float* aggp = (float*)(smem + 33280);                  // [4][64]

  const int tid = threadIdx.x;
  const int b = blockIdx.x >> 6;
  const int v = blockIdx.x & 63;

  if (tid < 64){
    int cnt = counts[v];
    if (tid < cnt){
      int e = bucket[v*64 + tid];
      srow[tid] = send[e];
      wrow[tid] = edges[(b*NE + e)*2 + 1];
    } else { srow[tid] = v; wrow[tid] = 0.0f; }
  }
  // stage both weight matrices (linear 16B copies from prepped ws)
  #pragma unroll
  for (int i = 0; i < 4; i++){
    int c = tid + i*256;
    const unsigned short* s = (c < 512) ? (W1g + c*8) : (W2g + (c-512)*8);
    unsigned short*       d = (c < 512) ? (W1  + c*8) : (W2  + (c-512)*8);
    *(s16x8*)d = *(const s16x8*)s;
  }
  __syncthreads();
  // stage A1: row i = edge slot; cols 0..31 = x[b,v,:], 32..63 = x[b,send_i,:]
  #pragma unroll
  for (int i = 0; i < 2; i++){
    int g = tid + i*256;           // 512 chunks = 64 rows x 8 chunks
    int row = g >> 3, c = g & 7;
    const float* src = (c < 4) ? (x + ((b*NV + v)*ND + c*8))
                               : (x + ((b*NV + srow[row])*ND + (c-4)*8));
    stage8(src, A1 + row*64 + ((c ^ (row & 7)) << 3));
  }
  __syncthreads();

  const int lane = tid & 63;
  const int w    = tid >> 6;       // wave id: rows 16w..16w+15
  const int l16  = lane & 15;
  const int l4   = lane >> 4;
  const int arow = w*16 + l16;

  float bias1[4], bias2[4];
  #pragma unroll
  for (int t = 0; t < 4; t++){ bias1[t] = b1g[t*16 + l16]; bias2[t] = b2g[t*16 + l16]; }

  // layer 1
  f32x4 acc[4] = {};
  #pragma unroll
  for (int ks = 0; ks < 2; ks++){
    s16x8 a = *(const s16x8*)(A1 + arow*64 + (((ks*4 + l4) ^ (arow & 7)) << 3));
    #pragma unroll
    for (int t = 0; t < 4; t++){
      int j = t*16 + l16;
      s16x8 bb = *(const s16x8*)(W1 + j*64 + (((ks*4 + l4) ^ (j & 7)) << 3));
      acc[t] = __builtin_amdgcn_mfma_f32_16x16x32_bf16(a, bb, acc[t], 0, 0, 0);
    }
  }
  #pragma unroll
  for (int t = 0; t < 4; t++){
    int col = t*16 + l16;
    #pragma unroll
    for (int r = 0; r < 4; r++){
      int row = w*16 + l4*4 + r;
      float hv = fmaxf(acc[t][r] + bias1[t], 0.0f);
      Hs[row*64 + (((col >> 3) ^ (row & 7)) << 3) + (col & 7)] = f2bf(hv);
    }
  }
  __syncthreads();
  // layer 2
  f32x4 acc2[4] = {};
  #pragma unroll
  for (int ks = 0; ks < 2; ks++){
    s16x8 a = *(const s16x8*)(Hs + arow*64 + (((ks*4 + l4) ^ (arow & 7)) << 3));
    #pragma unroll
    for (int t = 0; t < 4; t++){
      int j = t*16 + l16;
      s16x8 bb = *(const s16x8*)(W2 + j*64 + (((ks*4 + l4) ^ (j & 7)) << 3));
      acc2[t] = __builtin_amdgcn_mfma_f32_16x16x32_bf16(a, bb, acc2[t], 0, 0, 0);
    }
  }
  // msg = relu(.)*edge_w, column sums over this wave's 16 rows
  float csum[4];
  #pragma unroll
  for (int t = 0; t < 4; t++){
    float s = 0.0f;
    #pragma unroll
    for (int r = 0; r < 4; r++){
      int row = w*16 + l4*4 + r;
      float m = fmaxf(acc2[t][r] + bias2[t], 0.0f);
      s += m * wrow[row];
    }
    csum[t] = s;
  }
  #pragma unroll
  for (int t = 0; t < 4; t++){
    csum[t] += __shfl_xor(csum[t], 16);
    csum[t] += __shfl_xor(csum[t], 32);
  }
  if (l4 == 0){
    #pragma unroll
    for (int t = 0; t < 4; t++) aggp[w*64 + t*16 + l16] = csum[t];
  }
  __syncthreads();
  const int rowg = b*NV + v;
  if (tid < 64){
    float s = aggp[tid] + aggp[64 + tid] + aggp[128 + tid] + aggp[192 + tid];
    out_aug[rowg*96 + 32 + tid] = s;
  } else if (tid < 96){
    out_aug[rowg*96 + (tid - 64)] = x[rowg*ND + (tid - 64)];
  }
}

// ---------------- kernel 2: node MLP + heads + logp --------------------------

__global__ __launch_bounds__(256) void k_node(
    const unsigned short* __restrict__ F1g, const unsigned short* __restrict__ F2g,
    const unsigned short* __restrict__ HWg,
    const float* __restrict__ fc1b, const float* __restrict__ fc2b,
    const float* __restrict__ mub, const float* __restrict__ lsb,
    const float* __restrict__ aug,
    float* __restrict__ out0, float* __restrict__ out1)
{
  __shared__ __align__(16) unsigned char smem[59392];
  unsigned short* A  = (unsigned short*)(smem);           // [64][128] bf16 swz (K=96 padded)
  unsigned short* H1 = (unsigned short*)(smem + 16384);   // [64][64]
  unsigned short* H2 = (unsigned short*)(smem + 24576);   // [64][64]
  unsigned short* F1 = (unsigned short*)(smem + 32768);   // [64][128]
  unsigned short* F2 = (unsigned short*)(smem + 49152);   // [64][64]
  unsigned short* HW = (unsigned short*)(smem + 57344);   // [16][64]
  const int tid = threadIdx.x;
  const int g = blockIdx.x;

  #pragma unroll
  for (int i = 0; i < 7; i++){
    int c = tid + i*256;
    if (c < 1664){
      const unsigned short* s; unsigned short* d;
      if (c < 1024){ s = F1g + c*8;        d = F1 + c*8; }
      else if (c < 1536){ s = F2g + (c-1024)*8; d = F2 + (c-1024)*8; }
      else { s = HWg + (c-1536)*8; d = HW + (c-1536)*8; }
      *(s16x8*)d = *(const s16x8*)s;
    }
  }
  #pragma unroll
  for (int i = 0; i < 3; i++){
    int c = tid + i*256;               // 768 chunks = 64 rows x 12 chunks (96 f32)
    int row = c / 12, cc = c - row*12;
    stage8(aug + (g*64 + row)*96 + cc*8, A + row*128 + ((cc ^ (row & 7)) << 3));
  }
  __syncthreads();

  const int lane = tid & 63, w = tid >> 6;
  const int l16 = lane & 15, l4 = lane >> 4;
  const int arow = w*16 + l16;

  // fc1: K=96
  f32x4 acc[4] = {};
  #pragma unroll
  for (int ks = 0; ks < 3; ks++){
    s16x8 a = *(const s16x8*)(A + arow*128 + (((ks*4 + l4) ^ (arow & 7)) << 3));
    #pragma unroll
    for (int t = 0; t < 4; t++){
      int j = t*16 + l16;
      s16x8 bb = *(const s16x8*)(F1 + j*128 + (((ks*4 + l4) ^ (j & 7)) << 3));
      acc[t] = __builtin_amdgcn_mfma_f32_16x16x32_bf16(a, bb, acc[t], 0, 0, 0);
    }
  }
  #pragma unroll
  for (int t = 0; t < 4; t++){
    int col = t*16 + l16;
    #pragma unroll
    for (int r = 0; r < 4; r++){
      int row = w*16 + l4*4 + r;
      float hv = fmaxf(acc[t][r] + fc1b[col], 0.0f);
      H1[row*64 + (((col >> 3) ^ (row & 7)) << 3) + (col & 7)] = f2bf(hv);
    }
  }
  __syncthreads();
  // fc2: K=64
  f32x4 acc2[4] = {};
  #pragma unroll
  for (int ks = 0; ks < 2; ks++){
    s16x8 a = *(const s16x8*)(H1 + arow*64 + (((ks*4 + l4) ^ (arow & 7)) << 3));
    #pragma unroll
    for (int t = 0; t < 4; t++){
      int j = t*16 + l16;
      s16x8 bb = *(const s16x8*)(F2 + j*64 + (((ks*4 + l4) ^ (j & 7)) << 3));
      acc2[t] = __builtin_amdgcn_mfma_f32_16x16x32_bf16(a, bb, acc2[t], 0, 0, 0);
    }
  }
  #pragma unroll
  for (int t = 0; t < 4; t++){
    int col = t*16 + l16;
    #pragma unroll
    for (int r = 0; r < 4; r++){
      int row = w*16 + l4*4 + r;
      float hv = fmaxf(acc2[t][r] + fc2b[col], 0.0f);
      H2[row*64 + (((col >> 3) ^ (row & 7)) << 3) + (col & 7)] = f2bf(hv);
    }
  }
  __syncthreads();
  // head: [64rows]x[K=64]x[16 cols: mu0..7, ls0..7]
  f32x4 acc3 = {};
  #pragma unroll
  for (int ks = 0; ks < 2; ks++){
    s16x8 a = *(const s16x8*)(H2 + arow*64 + (((ks*4 + l4) ^ (arow & 7)) << 3));
    s16x8 bb = *(const s16x8*)(HW + l16*64 + (((ks*4 + l4) ^ (l16 & 7)) << 3));
    acc3 = __builtin_amdgcn_mfma_f32_16x16x32_bf16(a, bb, acc3, 0, 0, 0);
  }
  const int col = l16;
  float bias = (col < 8) ? mub[col] : lsb[col - 8];
  float term[4];
  #pragma unroll
  for (int r = 0; r < 4; r++){
    int growp = g*64 + w*16 + l4*4 + r;
    float val = acc3[r] + bias;
    if (col < 8){
      out0[growp*8 + col] = tanhf(val);
      float xm = -2.0f * val;
      float sp = fmaxf(xm, 0.0f) + log1pf(expf(-fabsf(xm)));  // softplus(-2mu)
      term[r] = -2.0f * (LOG2C - val - sp);
    } else {
      float lsv = fminf(fmaxf(val, -3.0f), 1.0f);
      term[r] = -lsv - HLOG2PI;
    }
  }
  #pragma unroll
  for (int r = 0; r < 4; r++){
    term[r] += __shfl_xor(term[r], 1);
    term[r] += __shfl_xor(term[r], 2);
    term[r] += __shfl_xor(term[r], 4);
    term[r] += __shfl_xor(term[r], 8);
  }
  if (l16 == 0){
    #pragma unroll
    for (int r = 0; r < 4; r++) out1[g*64 + w*16 + l4*4 + r] = term[r];
  }
}

// ---------------- launch -----------------------------------------------------

extern "C" void kernel_launch(void* const* d_in, const int* in_sizes, int n_in,
                              void* d_out, int out_size, void* d_ws, size_t ws_size,
                              hipStream_t stream) {
  const float* x     = (const float*)d_in[0];
  const float* edges = (const float*)d_in[1];
  const float* m1w   = (const float*)d_in[2];
  const float* m1b   = (const float*)d_in[3];
  const float* m2w   = (const float*)d_in[4];
  const float* m2b   = (const float*)d_in[5];
  const float* f1w   = (const float*)d_in[6];
  const float* f1b   = (const float*)d_in[7];
  const float* f2w   = (const float*)d_in[8];
  const float* f2b   = (const float*)d_in[9];
  const float* muw   = (const float*)d_in[10];
  const float* mub   = (const float*)d_in[11];
  const float* lsw   = (const float*)d_in[12];
  const float* lsb   = (const float*)d_in[13];
  const int*   send  = (const int*)d_in[14];
  const int*   recv  = (const int*)d_in[15];

  char* ws = (char*)d_ws;
  int* bucket = (int*)ws;                          // 16384 B
  int* counts = (int*)(ws + 16384);                // 256 B
  unsigned short* W1s = (unsigned short*)(ws + 16640);   // 8 KB
  unsigned short* W2s = (unsigned short*)(ws + 24832);   // 8 KB
  unsigned short* F1s = (unsigned short*)(ws + 33024);   // 16 KB
  unsigned short* F2s = (unsigned short*)(ws + 49408);   // 8 KB
  unsigned short* HWs = (unsigned short*)(ws + 57600);   // 2 KB

  float* out0    = (float*)d_out;                  // tanh(mu) [B,V,8]
  float* out1    = out0 + NB*NV*8;                 // logp [B,V]
  float* out_aug = out1 + NB*NV;                   // aug [B,V,96]

  k_bucket<<<1, 256, 0, stream>>>(recv, bucket, counts);
  k_prep<<<dim3(24, 5), 256, 0, stream>>>(m1w, m2w, f1w, f2w, muw, lsw,
                                          W1s, W2s, F1s, F2s, HWs);
  k_msg<<<NB*NV, 256, 0, stream>>>(x, edges, send, bucket, counts,
                                   W1s, W2s, m1b, m2b, out_aug);
  k_node<<<NB*NV/64, 256, 0, stream>>>(F1s, F2s, HWs, f1b, f2b, mub, lsb,
                                       out_aug, out0, out1);
}